// Round 6
// baseline (189.479 us; speedup 1.0000x reference)
//
#include <hip/hip_runtime.h>
#include <hip/hip_fp16.h>

// ClassicalGCN: 2-layer GCN, N=40000, E=640000, 128 -> 128(relu) -> 64, f32.
// Round 18: L2-resident sliced gathers. r17's cooperative fusion raced
// (cross-XCD) + fails graph capture -> abandoned. Instead attack the gather
// kernels' working set: h1 (10.24MB) > 4MB per-XCD L2, so ~60% of the 174MB
// layer-1 gather came from L3 (~47us). Now:
//  - layer-2 linearity: out = [dinv_d(sum dinv_s z_s + dinv_d z_d)]*W2 + b2,
//    so BOTH aggregations run over 128-wide fp16 tensors.
//  - packed-by-slice layout [4][N][32] (2.56MB/slice); slice s pinned to XCD
//    pair {2s,2s+1} via bid&7 heuristic -> per-XCD gather working set 2.56MB
//    -> L2-resident.
//  - agg1: in-loop dinv_s (uniform deg loads + rsqrt); z=relu(dn*acc+b1);
//    writes zp = f16(dn*z) so agg2 is a PURE SUM.
//  - k_out: assemble y2 rows from 4 slices -> LDS -> MFMA * W2T + b2 -> out.
// 5 launches: init, work1 (bucket || gemm1, r12-verified), agg1, agg2, out.
// Workspace ~36MB (r13 established >=41MB works).

#define N_NODES 40000
#define DIN 128
#define DH 128
#define DOUT 64
#define NEDGES 640000
#define CAP 64             // bin capacity; realized max degree ~35
#define NBUCKET 640        // 8 XCD groups x 80 chunks (r12 verified config)
#define I4_PER_CHUNK 2000  // 160000 int4 / 80 chunks
#define NODES_PER_XCD 5000
#define SLICE_HALFS (N_NODES * 32)   // halfs per 32-col slice region

typedef _Float16 f16x8 __attribute__((ext_vector_type(8)));
typedef float f32x4 __attribute__((ext_vector_type(4)));

// ---- init: zero deg + build WT1[n][k]=fp16(W1[k][n]), WT2[n][k]=fp16(W2[k][n])
__global__ void k_init(int* __restrict__ deg, const float* __restrict__ W1,
                       const float* __restrict__ W2,
                       _Float16* __restrict__ WT1, _Float16* __restrict__ WT2, int n) {
    int i = blockIdx.x * 256 + threadIdx.x;
    if (i < n) deg[i] = 0;
    if (i < DIN * DH) {
        int k = i >> 7, nn = i & 127;            // W1 row-major [k][n], n=128
        WT1[(size_t)nn * DIN + k] = (_Float16)W1[i];
    }
    if (i < DH * DOUT) {
        int k = i >> 6, nn = i & 63;             // W2 row-major [k][n], n=64
        WT2[(size_t)nn * DH + k] = (_Float16)W2[i];
    }
}

// ---- work1: blocks [0,640) = XCD-local bucket; [640,1265) = gemm1 MFMA ----
// gemm1 output h1p packed: h1p[(col>>5)*SLICE_HALFS + row*32 + (col&31)]
__global__ __launch_bounds__(256) void k_work1(
    const float* __restrict__ x, const _Float16* __restrict__ WT,
    _Float16* __restrict__ h1p,
    const int4* __restrict__ src4, const int4* __restrict__ dst4,
    int* __restrict__ deg, unsigned short* __restrict__ ssrc)
{
    if (blockIdx.x < NBUCKET) {
        // ---- bucket: this block only handles dst in its XCD's node range ----
        const int xg = blockIdx.x & 7;            // presumed XCD id (heuristic)
        const int c  = blockIdx.x >> 3;           // edge chunk 0..79
        const int lo = xg * NODES_PER_XCD, hi = lo + NODES_PER_XCD;
        const int e0 = c * I4_PER_CHUNK, e1 = e0 + I4_PER_CHUNK;
        for (int e = e0 + threadIdx.x; e < e1; e += 256) {
            int4 d = dst4[e];
            int4 s = src4[e];
            if (d.x >= lo && d.x < hi) {
                int p = atomicAdd(&deg[d.x], 1);
                if (p < CAP) ssrc[d.x * CAP + p] = (unsigned short)s.x;
            }
            if (d.y >= lo && d.y < hi) {
                int p = atomicAdd(&deg[d.y], 1);
                if (p < CAP) ssrc[d.y * CAP + p] = (unsigned short)s.y;
            }
            if (d.z >= lo && d.z < hi) {
                int p = atomicAdd(&deg[d.z], 1);
                if (p < CAP) ssrc[d.z * CAP + p] = (unsigned short)s.z;
            }
            if (d.w >= lo && d.w < hi) {
                int p = atomicAdd(&deg[d.w], 1);
                if (p < CAP) ssrc[d.w * CAP + p] = (unsigned short)s.w;
            }
        }
    } else {
        // ---- gemm1: one wave = 16 rows x 128 cols, K=128, UNSCALED out ----
        const int wave = (blockIdx.x - NBUCKET) * 4 + (threadIdx.x >> 6);  // 0..2499
        const int lane = threadIdx.x & 63;
        const int m = lane & 15, quad = lane >> 4;

        f32x4 acc[8];
#pragma unroll
        for (int nt = 0; nt < 8; ++nt) acc[nt] = (f32x4){0.f, 0.f, 0.f, 0.f};

        const float* xrow = x + (size_t)(wave * 16 + m) * DIN + quad * 8;
#pragma unroll
        for (int ks = 0; ks < 4; ++ks) {
            float4 xa = *(const float4*)(xrow + ks * 32);
            float4 xb = *(const float4*)(xrow + ks * 32 + 4);
            f16x8 a = { (_Float16)xa.x, (_Float16)xa.y, (_Float16)xa.z, (_Float16)xa.w,
                        (_Float16)xb.x, (_Float16)xb.y, (_Float16)xb.z, (_Float16)xb.w };
#pragma unroll
            for (int nt = 0; nt < 8; ++nt) {
                f16x8 b = *(const f16x8*)(WT + (size_t)(nt * 16 + m) * DIN + ks * 32 + quad * 8);
                acc[nt] = __builtin_amdgcn_mfma_f32_16x16x32_f16(a, b, acc[nt], 0, 0, 0);
            }
        }
#pragma unroll
        for (int r = 0; r < 4; ++r) {
            int orow = wave * 16 + quad * 4 + r;
#pragma unroll
            for (int nt = 0; nt < 8; ++nt) {
                // col = nt*16+m; slice = nt>>1; within = (nt&1)*16+m
                h1p[(size_t)(nt >> 1) * SLICE_HALFS + orow * 32 + (nt & 1) * 16 + m]
                    = (_Float16)acc[nt][r];
            }
        }
    }
}

// ---- agg1: sliced gather-sum of h1p with per-edge dinv; -> zp (pre-scaled)
// grid 10000: g=bid&7 -> XCD; slice=g>>1; tile=(bid>>3)*2+(g&1); 16 nodes/blk.
// 256 thr = 16 groups x 16 lanes; group = one node; lane = col pair.
__global__ __launch_bounds__(256) void k_agg1(
    const int* __restrict__ deg, const unsigned short* __restrict__ ssrc,
    const _Float16* __restrict__ h1p, const float* __restrict__ b1,
    _Float16* __restrict__ zp)
{
    const int g = blockIdx.x & 7;
    const int slice = g >> 1;
    const int tile = (blockIdx.x >> 3) * 2 + (g & 1);    // 0..2499
    const int grp = threadIdx.x >> 4;                    // 0..15 -> node
    const int lp  = threadIdx.x & 15;                    // col pair in slice
    const int node = tile * 16 + grp;

    const __half2* hp = (const __half2*)(h1p + (size_t)slice * SLICE_HALFS);
    const int dg = deg[node];
    const int cnt = min(dg, CAP);
    const float dn = rsqrtf((float)(dg + 1));
    float2 self = __half22float2(hp[node * 16 + lp]);
    float2 acc = { self.x * dn, self.y * dn };           // h1[d]*dinv_d
    const uint4* bin4 = (const uint4*)(ssrc + (size_t)node * CAP);
    int e = 0;
    for (; e + 8 <= cnt; e += 8) {
        uint4 pk = bin4[e >> 3];                         // uniform in group
        int s0 = pk.x & 0xFFFF, s1 = pk.x >> 16;
        int s2 = pk.y & 0xFFFF, s3 = pk.y >> 16;
        int s4 = pk.z & 0xFFFF, s5 = pk.z >> 16;
        int s6 = pk.w & 0xFFFF, s7 = pk.w >> 16;
        float w0 = rsqrtf((float)(deg[s0] + 1)), w1 = rsqrtf((float)(deg[s1] + 1));
        float w2 = rsqrtf((float)(deg[s2] + 1)), w3 = rsqrtf((float)(deg[s3] + 1));
        float w4 = rsqrtf((float)(deg[s4] + 1)), w5 = rsqrtf((float)(deg[s5] + 1));
        float w6 = rsqrtf((float)(deg[s6] + 1)), w7 = rsqrtf((float)(deg[s7] + 1));
        float2 v0 = __half22float2(hp[s0 * 16 + lp]);
        float2 v1 = __half22float2(hp[s1 * 16 + lp]);
        float2 v2 = __half22float2(hp[s2 * 16 + lp]);
        float2 v3 = __half22float2(hp[s3 * 16 + lp]);
        float2 v4 = __half22float2(hp[s4 * 16 + lp]);
        float2 v5 = __half22float2(hp[s5 * 16 + lp]);
        float2 v6 = __half22float2(hp[s6 * 16 + lp]);
        float2 v7 = __half22float2(hp[s7 * 16 + lp]);
        acc.x += (v0.x * w0 + v1.x * w1) + (v2.x * w2 + v3.x * w3)
               + (v4.x * w4 + v5.x * w5) + (v6.x * w6 + v7.x * w7);
        acc.y += (v0.y * w0 + v1.y * w1) + (v2.y * w2 + v3.y * w3)
               + (v4.y * w4 + v5.y * w5) + (v6.y * w6 + v7.y * w7);
    }
    for (; e < cnt; ++e) {
        int s = ssrc[(size_t)node * CAP + e];
        float wv = rsqrtf((float)(deg[s] + 1));
        float2 v = __half22float2(hp[s * 16 + lp]);
        acc.x += v.x * wv; acc.y += v.y * wv;
    }
    const int col = slice * 32 + 2 * lp;
    float2 bb = *(const float2*)(b1 + col);
    float vx = dn * acc.x + bb.x;
    float vy = dn * acc.y + bb.y;
    // zp = dinv_d * relu(...) : pre-scaled for layer-2 pure-sum gather
    float zx = (vx > 0.f ? vx : 0.f) * dn;
    float zy = (vy > 0.f ? vy : 0.f) * dn;
    ((__half2*)(zp + (size_t)slice * SLICE_HALFS))[node * 16 + lp]
        = __floats2half2_rn(zx, zy);
}

// ---- agg2: sliced PURE-SUM gather of zp -> y2p = f16(dn * (sum + self)) ----
__global__ __launch_bounds__(256) void k_agg2(
    const int* __restrict__ deg, const unsigned short* __restrict__ ssrc,
    const _Float16* __restrict__ zp, _Float16* __restrict__ y2p)
{
    const int g = blockIdx.x & 7;
    const int slice = g >> 1;
    const int tile = (blockIdx.x >> 3) * 2 + (g & 1);
    const int grp = threadIdx.x >> 4;
    const int lp  = threadIdx.x & 15;
    const int node = tile * 16 + grp;

    const __half2* hp = (const __half2*)(zp + (size_t)slice * SLICE_HALFS);
    const int dg = deg[node];
    const int cnt = min(dg, CAP);
    const float dn = rsqrtf((float)(dg + 1));
    float2 acc = __half22float2(hp[node * 16 + lp]);     // self: zp[d]
    const uint4* bin4 = (const uint4*)(ssrc + (size_t)node * CAP);
    int e = 0;
    for (; e + 8 <= cnt; e += 8) {
        uint4 pk = bin4[e >> 3];
        int s0 = pk.x & 0xFFFF, s1 = pk.x >> 16;
        int s2 = pk.y & 0xFFFF, s3 = pk.y >> 16;
        int s4 = pk.z & 0xFFFF, s5 = pk.z >> 16;
        int s6 = pk.w & 0xFFFF, s7 = pk.w >> 16;
        float2 v0 = __half22float2(hp[s0 * 16 + lp]);
        float2 v1 = __half22float2(hp[s1 * 16 + lp]);
        float2 v2 = __half22float2(hp[s2 * 16 + lp]);
        float2 v3 = __half22float2(hp[s3 * 16 + lp]);
        float2 v4 = __half22float2(hp[s4 * 16 + lp]);
        float2 v5 = __half22float2(hp[s5 * 16 + lp]);
        float2 v6 = __half22float2(hp[s6 * 16 + lp]);
        float2 v7 = __half22float2(hp[s7 * 16 + lp]);
        acc.x += ((v0.x + v1.x) + (v2.x + v3.x)) + ((v4.x + v5.x) + (v6.x + v7.x));
        acc.y += ((v0.y + v1.y) + (v2.y + v3.y)) + ((v4.y + v5.y) + (v6.y + v7.y));
    }
    for (; e < cnt; ++e) {
        int s = ssrc[(size_t)node * CAP + e];
        float2 v = __half22float2(hp[s * 16 + lp]);
        acc.x += v.x; acc.y += v.y;
    }
    ((__half2*)(y2p + (size_t)slice * SLICE_HALFS))[node * 16 + lp]
        = __floats2half2_rn(dn * acc.x, dn * acc.y);
}

// ---- out: assemble y2 rows (4 slices) -> LDS -> MFMA * WT2 + b2 -> f32 out ----
__global__ __launch_bounds__(256) void k_out(
    const _Float16* __restrict__ y2p, const _Float16* __restrict__ WT2,
    const float* __restrict__ b2, float* __restrict__ out)
{
    __shared__ _Float16 xs[16][136];   // +8 pad
    const int node0 = blockIdx.x * 16;
    const int nl = threadIdx.x >> 4;   // node_local 0..15
    const int j  = threadIdx.x & 15;   // 16B chunk id
    {
        const int slice = j >> 2, c8 = (j & 3) * 8;
        f16x8 v = *(const f16x8*)(y2p + (size_t)slice * SLICE_HALFS
                                  + (node0 + nl) * 32 + c8);
        *(f16x8*)&xs[nl][slice * 32 + c8] = v;
    }
    __syncthreads();

    const int wv = threadIdx.x >> 6;   // 0..3 -> out cols wv*16..+15
    const int lane = threadIdx.x & 63;
    const int m = lane & 15, quad = lane >> 4;
    f32x4 acc2 = (f32x4){0.f, 0.f, 0.f, 0.f};
#pragma unroll
    for (int ks = 0; ks < 4; ++ks) {
        f16x8 a = *(const f16x8*)&xs[m][ks * 32 + quad * 8];
        f16x8 b = *(const f16x8*)(WT2 + (size_t)(wv * 16 + m) * DH + ks * 32 + quad * 8);
        acc2 = __builtin_amdgcn_mfma_f32_16x16x32_f16(a, b, acc2, 0, 0, 0);
    }
    const float bv = b2[wv * 16 + m];
#pragma unroll
    for (int r = 0; r < 4; ++r) {
        int nrow = node0 + quad * 4 + r;
        out[(size_t)nrow * DOUT + wv * 16 + m] = acc2[r] + bv;
    }
}

extern "C" void kernel_launch(void* const* d_in, const int* in_sizes, int n_in,
                              void* d_out, int out_size, void* d_ws, size_t ws_size,
                              hipStream_t stream) {
    const float* x  = (const float*)d_in[0];
    const int*   ei = (const int*)d_in[1];   // [2, E] int32
    const float* W1 = (const float*)d_in[2];
    const float* b1 = (const float*)d_in[3];
    const float* W2 = (const float*)d_in[4];
    const float* b2 = (const float*)d_in[5];
    float* out = (float*)d_out;

    const int n = N_NODES, E = NEDGES;
    const int* src = ei;
    const int* dst = ei + E;

    // Workspace layout (bytes), ~36.1 MB, all 64B-aligned:
    char* ws = (char*)d_ws;
    int*            deg  = (int*)(ws + 0);                 // 160000
    _Float16*       WT1  = (_Float16*)(ws + 163840);       // 32768  fp16 W1^T
    _Float16*       WT2  = (_Float16*)(ws + 196608);       // 16384  fp16 W2^T
    unsigned short* ssrc = (unsigned short*)(ws + 212992); // 5.12MB ushort bins
    _Float16*       h1p  = (_Float16*)(ws + 5332992);      // 10.24MB packed [4][N][32]
    _Float16*       zp   = (_Float16*)(ws + 15572992);     // 10.24MB packed
    _Float16*       y2p  = (_Float16*)(ws + 25812992);     // 10.24MB packed

    k_init  <<<(n + 255) / 256, 256, 0, stream>>>(deg, W1, W2, WT1, WT2, n);
    k_work1 <<<NBUCKET + 625, 256, 0, stream>>>(x, WT1, h1p, (const int4*)src,
                                                (const int4*)dst, deg, ssrc);
    k_agg1  <<<10000, 256, 0, stream>>>(deg, ssrc, h1p, b1, zp);
    k_agg2  <<<10000, 256, 0, stream>>>(deg, ssrc, zp, y2p);
    k_out   <<<n / 16, 256, 0, stream>>>(y2p, WT2, b2, out);
}

// Round 7
// 181.024 us; speedup vs baseline: 1.0467x; 1.0467x over previous
//
#include <hip/hip_runtime.h>
#include <hip/hip_fp16.h>

// ClassicalGCN: 2-layer GCN, N=40000, E=640000, 128 -> 128(relu) -> 64, f32.
// Round 19: r15 base (best verified, 171.9us) minus two dispatch gaps.
// Ledger r12-r18: every kernel-level restructure lands 172-190us; only
// launch-count and phase-deletion ever moved total. r18's slicing regressed
// (gathers are latency-bound, already cache-served: r15 FETCH=61MB for
// 164MB logical). So:
//  - k_init DELETED: deg-zero -> hipMemsetAsync (graph memset node);
//    WT1/WT2 fp16 transposes -> 8 extra blocks in k_bkt_cvt (hidden).
//  - k_bkt_cvt: r15 verified (2560 bucket + 1250 cvt blocks) + 8 WT blocks.
//  - k_agg_g12: r15 verified fused agg+gemm1+gemm2 (16 waves x 1 node),
//    with shfl-free uniform uint4 bin loads + uniform deg[s] loads (r16/r18
//    verified path).
//  - k_agg2: r16 verified (uniform loads, half-wave row pairing).
// 3 kernels + 1 memset. Workspace ~20.7MB, r12-verified offsets.

#define N_NODES 40000
#define DIN 128
#define DH 128
#define DOUT 64
#define NEDGES 640000
#define CAP 64             // bin capacity; realized max degree ~35
#define NBUCKET 2560       // 8 XCD groups x 320 chunks (r15 verified)
#define I4_PER_CHUNK 500   // 160000 int4 / 320 chunks
#define NODES_PER_XCD 5000
#define NCVT 1250          // x->fp16 convert blocks
#define NWT 8              // WT1/WT2 transpose blocks

typedef _Float16 f16x8 __attribute__((ext_vector_type(8)));
typedef float f32x4 __attribute__((ext_vector_type(4)));

// ---- blocks [0,NBUCKET): bucket; [NBUCKET,+NCVT): x->fp16; last NWT: WT ----
__global__ __launch_bounds__(256) void k_bkt_cvt(
    const float* __restrict__ x, _Float16* __restrict__ xh,
    const int4* __restrict__ src4, const int4* __restrict__ dst4,
    int* __restrict__ deg, unsigned short* __restrict__ ssrc,
    const float* __restrict__ W1, const float* __restrict__ W2,
    _Float16* __restrict__ WT1, _Float16* __restrict__ WT2)
{
    if (blockIdx.x < NBUCKET) {
        // ---- bucket: this block only handles dst in its XCD's node range ----
        const int xg = blockIdx.x & 7;            // presumed XCD id (heuristic)
        const int c  = blockIdx.x >> 3;           // edge chunk 0..319
        const int lo = xg * NODES_PER_XCD, hi = lo + NODES_PER_XCD;
        const int e0 = c * I4_PER_CHUNK, e1 = e0 + I4_PER_CHUNK;
        for (int e = e0 + threadIdx.x; e < e1; e += 256) {
            int4 d = dst4[e];
            int4 s = src4[e];
            if (d.x >= lo && d.x < hi) {
                int p = atomicAdd(&deg[d.x], 1);
                if (p < CAP) ssrc[d.x * CAP + p] = (unsigned short)s.x;
            }
            if (d.y >= lo && d.y < hi) {
                int p = atomicAdd(&deg[d.y], 1);
                if (p < CAP) ssrc[d.y * CAP + p] = (unsigned short)s.y;
            }
            if (d.z >= lo && d.z < hi) {
                int p = atomicAdd(&deg[d.z], 1);
                if (p < CAP) ssrc[d.z * CAP + p] = (unsigned short)s.z;
            }
            if (d.w >= lo && d.w < hi) {
                int p = atomicAdd(&deg[d.w], 1);
                if (p < CAP) ssrc[d.w * CAP + p] = (unsigned short)s.w;
            }
        }
    } else if (blockIdx.x < NBUCKET + NCVT) {
        // ---- convert: 16 f32 per thread, coalesced float4 -> f16x8 ----
        const size_t base = ((size_t)(blockIdx.x - NBUCKET) * 256 + threadIdx.x) * 16;
        float4 a0 = *(const float4*)(x + base);
        float4 a1 = *(const float4*)(x + base + 4);
        float4 a2 = *(const float4*)(x + base + 8);
        float4 a3 = *(const float4*)(x + base + 12);
        f16x8 o0 = { (_Float16)a0.x, (_Float16)a0.y, (_Float16)a0.z, (_Float16)a0.w,
                     (_Float16)a1.x, (_Float16)a1.y, (_Float16)a1.z, (_Float16)a1.w };
        f16x8 o1 = { (_Float16)a2.x, (_Float16)a2.y, (_Float16)a2.z, (_Float16)a2.w,
                     (_Float16)a3.x, (_Float16)a3.y, (_Float16)a3.z, (_Float16)a3.w };
        *(f16x8*)(xh + base)     = o0;
        *(f16x8*)(xh + base + 8) = o1;
    } else {
        // ---- WT transposes: WT1[n][k]=fp16(W1[k][n]), WT2[n][k]=fp16(W2[k][n])
        const int b = blockIdx.x - NBUCKET - NCVT;   // 0..7
        for (int i = b * 256 + threadIdx.x; i < DIN * DH; i += NWT * 256) {
            int k = i >> 7, nn = i & 127;
            WT1[nn * DIN + k] = (_Float16)W1[i];
        }
        for (int i = b * 256 + threadIdx.x; i < DH * DOUT; i += NWT * 256) {
            int k = i >> 6, nn = i & 63;
            WT2[nn * DH + k] = (_Float16)W2[i];
        }
    }
}

// ---- gather xh (agg) + gemm1(+b1,relu) + gemm2(*dinv) fused.
// Block = 16 nodes, ONE node per wave (16 waves, 1024 thr).
__global__ __launch_bounds__(1024) void k_agg_g12(
    const int* __restrict__ deg, const unsigned short* __restrict__ ssrc,
    const __half* __restrict__ xh, const float* __restrict__ b1,
    const _Float16* __restrict__ WT1, const _Float16* __restrict__ WT2,
    __half* __restrict__ h2)
{
    __shared__ _Float16 ys[16][136];   // aggregated input tile (+8 pad)
    __shared__ _Float16 zs[16][136];   // post-relu hidden tile (+8 pad)
    const int w = threadIdx.x >> 6;    // wave 0..15 -> node index in block
    const int lane = threadIdx.x & 63;
    const int node0 = blockIdx.x * 16;
    const int node = node0 + w;
    const __half2* hp = (const __half2*)xh;   // 64 half2 per row

    const int dg = deg[node];
    const int cnt = min(dg, CAP);
    const float dn = rsqrtf((float)(dg + 1));
    float2 self = __half22float2(hp[(size_t)node * 64 + lane]);
    float2 acc = { self.x * dn, self.y * dn };   // self-loop: xh[d]*dinv_d
    const uint4* bin4 = (const uint4*)(ssrc + (size_t)node * CAP);
    int e = 0;
    for (; e + 8 <= cnt; e += 8) {
        uint4 pk = bin4[e >> 3];                 // wave-uniform -> broadcast
        int s0 = pk.x & 0xFFFF, s1 = pk.x >> 16;
        int s2 = pk.y & 0xFFFF, s3 = pk.y >> 16;
        int s4 = pk.z & 0xFFFF, s5 = pk.z >> 16;
        int s6 = pk.w & 0xFFFF, s7 = pk.w >> 16;
        float w0 = rsqrtf((float)(deg[s0] + 1)), w1 = rsqrtf((float)(deg[s1] + 1));
        float w2 = rsqrtf((float)(deg[s2] + 1)), w3 = rsqrtf((float)(deg[s3] + 1));
        float w4 = rsqrtf((float)(deg[s4] + 1)), w5 = rsqrtf((float)(deg[s5] + 1));
        float w6 = rsqrtf((float)(deg[s6] + 1)), w7 = rsqrtf((float)(deg[s7] + 1));
        float2 v0 = __half22float2(hp[(size_t)s0 * 64 + lane]);
        float2 v1 = __half22float2(hp[(size_t)s1 * 64 + lane]);
        float2 v2 = __half22float2(hp[(size_t)s2 * 64 + lane]);
        float2 v3 = __half22float2(hp[(size_t)s3 * 64 + lane]);
        float2 v4 = __half22float2(hp[(size_t)s4 * 64 + lane]);
        float2 v5 = __half22float2(hp[(size_t)s5 * 64 + lane]);
        float2 v6 = __half22float2(hp[(size_t)s6 * 64 + lane]);
        float2 v7 = __half22float2(hp[(size_t)s7 * 64 + lane]);
        acc.x += (v0.x * w0 + v1.x * w1) + (v2.x * w2 + v3.x * w3)
               + (v4.x * w4 + v5.x * w5) + (v6.x * w6 + v7.x * w7);
        acc.y += (v0.y * w0 + v1.y * w1) + (v2.y * w2 + v3.y * w3)
               + (v4.y * w4 + v5.y * w5) + (v6.y * w6 + v7.y * w7);
    }
    for (; e < cnt; ++e) {
        int s = ssrc[(size_t)node * CAP + e];
        float wv = rsqrtf((float)(deg[s] + 1));
        float2 v = __half22float2(hp[(size_t)s * 64 + lane]);
        acc.x += v.x * wv; acc.y += v.y * wv;
    }
    // y = dn * acc  (aggregated input; bias applied after gemm1)
    ys[w][2 * lane]     = (_Float16)(dn * acc.x);
    ys[w][2 * lane + 1] = (_Float16)(dn * acc.y);
    __syncthreads();

    const int m = lane & 15, quad = lane >> 4;
    if (w < 8) {
        // ---- gemm1 tile: wave w covers hidden cols w*16 .. w*16+15 ----
        f32x4 acc1 = (f32x4){0.f, 0.f, 0.f, 0.f};
#pragma unroll
        for (int ks = 0; ks < 4; ++ks) {
            f16x8 a = *(const f16x8*)&ys[m][ks * 32 + quad * 8];
            f16x8 b = *(const f16x8*)(WT1 + (size_t)(w * 16 + m) * DIN + ks * 32 + quad * 8);
            acc1 = __builtin_amdgcn_mfma_f32_16x16x32_f16(a, b, acc1, 0, 0, 0);
        }
        float bias = b1[w * 16 + m];
#pragma unroll
        for (int r = 0; r < 4; ++r) {
            float v = acc1[r] + bias;
            zs[quad * 4 + r][w * 16 + m] = (_Float16)(v > 0.f ? v : 0.f);
        }
    }
    __syncthreads();

    if (w < 4) {
        // ---- gemm2 tile: wave w covers out cols w*16 .. w*16+15 ----
        f32x4 acc2 = (f32x4){0.f, 0.f, 0.f, 0.f};
#pragma unroll
        for (int ks = 0; ks < 4; ++ks) {
            f16x8 a = *(const f16x8*)&zs[m][ks * 32 + quad * 8];
            f16x8 b = *(const f16x8*)(WT2 + (size_t)(w * 16 + m) * DH + ks * 32 + quad * 8);
            acc2 = __builtin_amdgcn_mfma_f32_16x16x32_f16(a, b, acc2, 0, 0, 0);
        }
#pragma unroll
        for (int r = 0; r < 4; ++r) {
            int nrow = node0 + quad * 4 + r;
            float dnr = rsqrtf((float)(deg[nrow] + 1));
            h2[(size_t)nrow * DOUT + w * 16 + m] = (__half)(acc2[r] * dnr);
        }
    }
}

// ---- layer-2 gather-reduce: half-wave row pairing + uniform packed indices ----
__global__ __launch_bounds__(256) void k_agg2(
    const int* __restrict__ deg, const unsigned short* __restrict__ ssrc,
    const __half* __restrict__ h, const float* __restrict__ b2,
    float* __restrict__ out)
{
    const int node = blockIdx.x * 4 + (threadIdx.x >> 6);
    const int lane = threadIdx.x & 63;
    const int half = lane >> 5;        // 0: even edges, 1: odd edges
    const int lp = lane & 31;          // col-pair index (cols 2lp, 2lp+1)
    const int dg = deg[node];
    const int cnt = min(dg, CAP);
    const __half2* hp = (const __half2*)h;   // 32 half2 per 64-col row

    float2 acc;
    if (half == 0) acc = __half22float2(hp[(size_t)node * 32 + lp]);  // self (scaled)
    else           acc = make_float2(0.f, 0.f);

    const uint4* bin4 = (const uint4*)(ssrc + (size_t)node * CAP);
    int e = 0;
    for (; e + 8 <= cnt; e += 8) {
        uint4 pk = bin4[e >> 3];                 // uniform -> HW broadcast
        int sa, sb, sc, sd;
        if (half == 0) { sa = pk.x & 0xFFFF; sb = pk.y & 0xFFFF;
                         sc = pk.z & 0xFFFF; sd = pk.w & 0xFFFF; }
        else           { sa = pk.x >> 16;    sb = pk.y >> 16;
                         sc = pk.z >> 16;    sd = pk.w >> 16; }
        float2 v0 = __half22float2(hp[(size_t)sa * 32 + lp]);
        float2 v1 = __half22float2(hp[(size_t)sb * 32 + lp]);
        float2 v2 = __half22float2(hp[(size_t)sc * 32 + lp]);
        float2 v3 = __half22float2(hp[(size_t)sd * 32 + lp]);
        acc.x += (v0.x + v1.x) + (v2.x + v3.x);
        acc.y += (v0.y + v1.y) + (v2.y + v3.y);
    }
    for (; e + 2 <= cnt; e += 2) {     // paired tail: uniform 2B loads
        int s = ssrc[(size_t)node * CAP + e + half];
        float2 v = __half22float2(hp[(size_t)s * 32 + lp]);
        acc.x += v.x; acc.y += v.y;
    }
    if (e < cnt) {                     // odd leftover: half 0 only
        int s = ssrc[(size_t)node * CAP + e];
        if (half == 0) {
            float2 v = __half22float2(hp[(size_t)s * 32 + lp]);
            acc.x += v.x; acc.y += v.y;
        }
    }
    // combine half-waves
    acc.x += __shfl_xor(acc.x, 32);
    acc.y += __shfl_xor(acc.y, 32);
    if (half == 0) {
        float dn = rsqrtf((float)(dg + 1));
        float2 o;
        o.x = dn * acc.x + b2[2 * lp];
        o.y = dn * acc.y + b2[2 * lp + 1];
        *(float2*)&out[(size_t)node * 64 + 2 * lp] = o;
    }
}

extern "C" void kernel_launch(void* const* d_in, const int* in_sizes, int n_in,
                              void* d_out, int out_size, void* d_ws, size_t ws_size,
                              hipStream_t stream) {
    const float* x  = (const float*)d_in[0];
    const int*   ei = (const int*)d_in[1];   // [2, E] int32
    const float* W1 = (const float*)d_in[2];
    const float* b1 = (const float*)d_in[3];
    const float* W2 = (const float*)d_in[4];
    const float* b2 = (const float*)d_in[5];
    float* out = (float*)d_out;

    const int n = N_NODES, E = NEDGES;
    const int* src = ei;
    const int* dst = ei + E;

    // Workspace layout (bytes), ~20.7 MB (byte-identical to verified r12):
    char* ws = (char*)d_ws;
    int*            deg  = (int*)(ws + 0);                 // 160000
    _Float16*       WT1  = (_Float16*)(ws + 163840);       // 32768  fp16 W1^T
    _Float16*       WT2  = (_Float16*)(ws + 196608);       // 16384  fp16 W2^T
    unsigned short* ssrc = (unsigned short*)(ws + 212992); // 5.12MB ushort bins
    _Float16*       xh   = (_Float16*)(ws + 5332992);      // 10.24MB fp16 x
    __half*         h2   = (__half*)(ws + 15572992);       // 5.12MB fp16 (scaled)

    hipMemsetAsync(deg, 0, N_NODES * sizeof(int), stream);
    k_bkt_cvt <<<NBUCKET + NCVT + NWT, 256, 0, stream>>>(x, xh, (const int4*)src,
                                                         (const int4*)dst, deg, ssrc,
                                                         W1, W2, WT1, WT2);
    k_agg_g12 <<<n / 16, 1024, 0, stream>>>(deg, ssrc, (const __half*)xh, b1,
                                            WT1, WT2, h2);
    k_agg2    <<<n / 4,  256, 0, stream>>>(deg, ssrc, h2, b2, out);
}

// Round 8
// 166.680 us; speedup vs baseline: 1.1368x; 1.0861x over previous
//
#include <hip/hip_runtime.h>
#include <hip/hip_fp16.h>

// ClassicalGCN: 2-layer GCN, N=40000, E=640000, 128 -> 128(relu) -> 64, f32.
// Round 20: multiply gather MLP. r19 postmortem: (a) the constant ~45us in
// every run is the harness's 256MiB workspace re-poison fill (visible in
// counters), NOT launch gaps -> only Sum(kernels) matters; (b) agg_g12
// regressed because uniform deg[s]+rsqrtf serialized weight calc on the
// wave critical path. Fix: group-split gathers:
//  - k_agg_g12: 4 waves x 4 nodes/wave as 16-lane GROUPS (16 lanes x f16x8
//    = full 128-col row per load). 4 indices per group-uniform 8B bin load,
//    zero-weight pads to wave-max cnt -> 16 independent rows in flight/wave
//    (vs 8 on one stream). Then in-block gemm1(+b1,relu)+gemm2(*dinv) as
//    r12-shape (2 gemm1 tiles/wave, 1 gemm2 tile/wave).
//  - k_agg2: 8-lane groups (full 64-col row), 32 nodes/block, same scheme.
//  - k_bkt_cvt: r19-verified (bucket 2560 + cvt 1250 + WT 8), unchanged.
// 3 kernels + deg memset. Workspace ~20.7MB, r12-verified offsets.

#define N_NODES 40000
#define DIN 128
#define DH 128
#define DOUT 64
#define NEDGES 640000
#define CAP 64             // bin capacity; realized max degree ~35
#define NBUCKET 2560       // 8 XCD groups x 320 chunks (r15/r19 verified)
#define I4_PER_CHUNK 500   // 160000 int4 / 320 chunks
#define NODES_PER_XCD 5000
#define NCVT 1250          // x->fp16 convert blocks
#define NWT 8              // WT1/WT2 transpose blocks

typedef _Float16 f16x8 __attribute__((ext_vector_type(8)));
typedef float f32x4 __attribute__((ext_vector_type(4)));

// ---- blocks [0,NBUCKET): bucket; [NBUCKET,+NCVT): x->fp16; last NWT: WT ----
__global__ __launch_bounds__(256) void k_bkt_cvt(
    const float* __restrict__ x, _Float16* __restrict__ xh,
    const int4* __restrict__ src4, const int4* __restrict__ dst4,
    int* __restrict__ deg, unsigned short* __restrict__ ssrc,
    const float* __restrict__ W1, const float* __restrict__ W2,
    _Float16* __restrict__ WT1, _Float16* __restrict__ WT2)
{
    if (blockIdx.x < NBUCKET) {
        // ---- bucket: this block only handles dst in its XCD's node range ----
        const int xg = blockIdx.x & 7;            // presumed XCD id (heuristic)
        const int c  = blockIdx.x >> 3;           // edge chunk 0..319
        const int lo = xg * NODES_PER_XCD, hi = lo + NODES_PER_XCD;
        const int e0 = c * I4_PER_CHUNK, e1 = e0 + I4_PER_CHUNK;
        for (int e = e0 + threadIdx.x; e < e1; e += 256) {
            int4 d = dst4[e];
            int4 s = src4[e];
            if (d.x >= lo && d.x < hi) {
                int p = atomicAdd(&deg[d.x], 1);
                if (p < CAP) ssrc[d.x * CAP + p] = (unsigned short)s.x;
            }
            if (d.y >= lo && d.y < hi) {
                int p = atomicAdd(&deg[d.y], 1);
                if (p < CAP) ssrc[d.y * CAP + p] = (unsigned short)s.y;
            }
            if (d.z >= lo && d.z < hi) {
                int p = atomicAdd(&deg[d.z], 1);
                if (p < CAP) ssrc[d.z * CAP + p] = (unsigned short)s.z;
            }
            if (d.w >= lo && d.w < hi) {
                int p = atomicAdd(&deg[d.w], 1);
                if (p < CAP) ssrc[d.w * CAP + p] = (unsigned short)s.w;
            }
        }
    } else if (blockIdx.x < NBUCKET + NCVT) {
        // ---- convert: 16 f32 per thread, coalesced float4 -> f16x8 ----
        const size_t base = ((size_t)(blockIdx.x - NBUCKET) * 256 + threadIdx.x) * 16;
        float4 a0 = *(const float4*)(x + base);
        float4 a1 = *(const float4*)(x + base + 4);
        float4 a2 = *(const float4*)(x + base + 8);
        float4 a3 = *(const float4*)(x + base + 12);
        f16x8 o0 = { (_Float16)a0.x, (_Float16)a0.y, (_Float16)a0.z, (_Float16)a0.w,
                     (_Float16)a1.x, (_Float16)a1.y, (_Float16)a1.z, (_Float16)a1.w };
        f16x8 o1 = { (_Float16)a2.x, (_Float16)a2.y, (_Float16)a2.z, (_Float16)a2.w,
                     (_Float16)a3.x, (_Float16)a3.y, (_Float16)a3.z, (_Float16)a3.w };
        *(f16x8*)(xh + base)     = o0;
        *(f16x8*)(xh + base + 8) = o1;
    } else {
        // ---- WT transposes: WT1[n][k]=fp16(W1[k][n]), WT2[n][k]=fp16(W2[k][n])
        const int b = blockIdx.x - NBUCKET - NCVT;   // 0..7
        for (int i = b * 256 + threadIdx.x; i < DIN * DH; i += NWT * 256) {
            int k = i >> 7, nn = i & 127;
            WT1[nn * DIN + k] = (_Float16)W1[i];
        }
        for (int i = b * 256 + threadIdx.x; i < DH * DOUT; i += NWT * 256) {
            int k = i >> 6, nn = i & 63;
            WT2[nn * DH + k] = (_Float16)W2[i];
        }
    }
}

// ---- agg1 (4 group-streams/wave) + gemm1(+b1,relu) + gemm2(*dinv) fused.
// Block = 16 nodes = 4 waves x 4 groups(16 lanes); group g owns one node;
// lane gl covers halfs [gl*8, gl*8+8) of the 128-col row.
__global__ __launch_bounds__(256) void k_agg_g12(
    const int* __restrict__ deg, const unsigned short* __restrict__ ssrc,
    const _Float16* __restrict__ xh, const float* __restrict__ b1,
    const _Float16* __restrict__ WT1, const _Float16* __restrict__ WT2,
    _Float16* __restrict__ h2)
{
    __shared__ _Float16 ys[16][136];   // aggregated input tile (+8 pad)
    __shared__ _Float16 zs[16][136];   // post-relu hidden tile (+8 pad)
    const int w = threadIdx.x >> 6;    // wave 0..3
    const int lane = threadIdx.x & 63;
    const int g  = lane >> 4;          // group 0..3 -> node
    const int gl = lane & 15;          // lane in group -> col chunk
    const int node0 = blockIdx.x * 16;
    const int node = node0 + w * 4 + g;

    const int dg = deg[node];
    const int cnt = min(dg, CAP);
    const float dn = rsqrtf((float)(dg + 1));

    float ac[8];
    {
        f16x8 self = *(const f16x8*)(xh + (size_t)node * DIN + gl * 8);
#pragma unroll
        for (int j = 0; j < 8; ++j) ac[j] = dn * (float)self[j];  // dinv_d * x_d
    }
    // wave-max cnt (4 groups) so all lanes loop together; pads weight 0
    int mc = cnt;
    mc = max(mc, __shfl_xor(mc, 16));
    mc = max(mc, __shfl_xor(mc, 32));

    const unsigned short* bin = ssrc + (size_t)node * CAP;
    for (int e = 0; e < mc; e += 4) {
        unsigned long long pk = *(const unsigned long long*)(bin + e);  // group-uniform
        int s0 = (int)(pk & 0xFFFF),         s1 = (int)((pk >> 16) & 0xFFFF);
        int s2 = (int)((pk >> 32) & 0xFFFF), s3 = (int)((pk >> 48) & 0xFFFF);
        s0 = (e + 0 < cnt) ? s0 : 0;
        s1 = (e + 1 < cnt) ? s1 : 0;
        s2 = (e + 2 < cnt) ? s2 : 0;
        s3 = (e + 3 < cnt) ? s3 : 0;
        f16x8 r0 = *(const f16x8*)(xh + (size_t)s0 * DIN + gl * 8);
        f16x8 r1 = *(const f16x8*)(xh + (size_t)s1 * DIN + gl * 8);
        f16x8 r2 = *(const f16x8*)(xh + (size_t)s2 * DIN + gl * 8);
        f16x8 r3 = *(const f16x8*)(xh + (size_t)s3 * DIN + gl * 8);
        float w0 = (e + 0 < cnt) ? rsqrtf((float)(deg[s0] + 1)) : 0.f;
        float w1 = (e + 1 < cnt) ? rsqrtf((float)(deg[s1] + 1)) : 0.f;
        float w2 = (e + 2 < cnt) ? rsqrtf((float)(deg[s2] + 1)) : 0.f;
        float w3 = (e + 3 < cnt) ? rsqrtf((float)(deg[s3] + 1)) : 0.f;
#pragma unroll
        for (int j = 0; j < 8; ++j)
            ac[j] += (w0 * (float)r0[j] + w1 * (float)r1[j])
                   + (w2 * (float)r2[j] + w3 * (float)r3[j]);
    }
    // ys row = dn * ac  (bias after gemm1)
    {
        f16x8 o;
#pragma unroll
        for (int j = 0; j < 8; ++j) o[j] = (_Float16)(dn * ac[j]);
        *(f16x8*)&ys[w * 4 + g][gl * 8] = o;
    }
    __syncthreads();

    const int m = lane & 15, quad = lane >> 4;
#pragma unroll
    for (int t = 0; t < 2; ++t) {
        // ---- gemm1: wave w covers hidden cols (2w+t)*16 .. +15 ----
        const int nt = w * 2 + t;
        f32x4 acc1 = (f32x4){0.f, 0.f, 0.f, 0.f};
#pragma unroll
        for (int ks = 0; ks < 4; ++ks) {
            f16x8 a = *(const f16x8*)&ys[m][ks * 32 + quad * 8];
            f16x8 b = *(const f16x8*)(WT1 + (size_t)(nt * 16 + m) * DIN + ks * 32 + quad * 8);
            acc1 = __builtin_amdgcn_mfma_f32_16x16x32_f16(a, b, acc1, 0, 0, 0);
        }
        float bias = b1[nt * 16 + m];
#pragma unroll
        for (int r = 0; r < 4; ++r) {
            float v = acc1[r] + bias;
            zs[quad * 4 + r][nt * 16 + m] = (_Float16)(v > 0.f ? v : 0.f);
        }
    }
    __syncthreads();

    {
        // ---- gemm2: wave w covers out cols w*16 .. +15; h2 pre-scaled ----
        f32x4 acc2 = (f32x4){0.f, 0.f, 0.f, 0.f};
#pragma unroll
        for (int ks = 0; ks < 4; ++ks) {
            f16x8 a = *(const f16x8*)&zs[m][ks * 32 + quad * 8];
            f16x8 b = *(const f16x8*)(WT2 + (size_t)(w * 16 + m) * DH + ks * 32 + quad * 8);
            acc2 = __builtin_amdgcn_mfma_f32_16x16x32_f16(a, b, acc2, 0, 0, 0);
        }
#pragma unroll
        for (int r = 0; r < 4; ++r) {
            int nrow = node0 + quad * 4 + r;
            float dnr = rsqrtf((float)(deg[nrow] + 1));
            h2[(size_t)nrow * DOUT + w * 16 + m] = (_Float16)(acc2[r] * dnr);
        }
    }
}

// ---- agg2: 8 group-streams/wave over pre-scaled h2 (64 cols = 8 lanes x 8).
// Block = 32 nodes = 4 waves x 8 groups(8 lanes).
__global__ __launch_bounds__(256) void k_agg2(
    const int* __restrict__ deg, const unsigned short* __restrict__ ssrc,
    const _Float16* __restrict__ h2, const float* __restrict__ b2,
    float* __restrict__ out)
{
    const int w = threadIdx.x >> 6;
    const int lane = threadIdx.x & 63;
    const int g  = lane >> 3;          // group 0..7 -> node
    const int gl = lane & 7;           // col chunk (8 halfs)
    const int node = blockIdx.x * 32 + w * 8 + g;

    const int dg = deg[node];
    const int cnt = min(dg, CAP);
    const float dn = rsqrtf((float)(dg + 1));

    float ac[8];
    {
        f16x8 self = *(const f16x8*)(h2 + (size_t)node * DOUT + gl * 8);
#pragma unroll
        for (int j = 0; j < 8; ++j) ac[j] = (float)self[j];   // self (pre-scaled)
    }
    int mc = cnt;
    mc = max(mc, __shfl_xor(mc, 8));
    mc = max(mc, __shfl_xor(mc, 16));
    mc = max(mc, __shfl_xor(mc, 32));

    const unsigned short* bin = ssrc + (size_t)node * CAP;
    for (int e = 0; e < mc; e += 4) {
        unsigned long long pk = *(const unsigned long long*)(bin + e);  // group-uniform
        int s0 = (int)(pk & 0xFFFF),         s1 = (int)((pk >> 16) & 0xFFFF);
        int s2 = (int)((pk >> 32) & 0xFFFF), s3 = (int)((pk >> 48) & 0xFFFF);
        s0 = (e + 0 < cnt) ? s0 : 0;
        s1 = (e + 1 < cnt) ? s1 : 0;
        s2 = (e + 2 < cnt) ? s2 : 0;
        s3 = (e + 3 < cnt) ? s3 : 0;
        float m0 = (e + 0 < cnt) ? 1.f : 0.f;
        float m1 = (e + 1 < cnt) ? 1.f : 0.f;
        float m2 = (e + 2 < cnt) ? 1.f : 0.f;
        float m3 = (e + 3 < cnt) ? 1.f : 0.f;
        f16x8 r0 = *(const f16x8*)(h2 + (size_t)s0 * DOUT + gl * 8);
        f16x8 r1 = *(const f16x8*)(h2 + (size_t)s1 * DOUT + gl * 8);
        f16x8 r2 = *(const f16x8*)(h2 + (size_t)s2 * DOUT + gl * 8);
        f16x8 r3 = *(const f16x8*)(h2 + (size_t)s3 * DOUT + gl * 8);
#pragma unroll
        for (int j = 0; j < 8; ++j)
            ac[j] += (m0 * (float)r0[j] + m1 * (float)r1[j])
                   + (m2 * (float)r2[j] + m3 * (float)r3[j]);
    }
    // out = dn*ac + b2
    float4 ba = *(const float4*)(b2 + gl * 8);
    float4 bb = *(const float4*)(b2 + gl * 8 + 4);
    float4 o0 = { dn * ac[0] + ba.x, dn * ac[1] + ba.y,
                  dn * ac[2] + ba.z, dn * ac[3] + ba.w };
    float4 o1 = { dn * ac[4] + bb.x, dn * ac[5] + bb.y,
                  dn * ac[6] + bb.z, dn * ac[7] + bb.w };
    float* orow = out + (size_t)node * DOUT + gl * 8;
    *(float4*)orow = o0;
    *(float4*)(orow + 4) = o1;
}

extern "C" void kernel_launch(void* const* d_in, const int* in_sizes, int n_in,
                              void* d_out, int out_size, void* d_ws, size_t ws_size,
                              hipStream_t stream) {
    const float* x  = (const float*)d_in[0];
    const int*   ei = (const int*)d_in[1];   // [2, E] int32
    const float* W1 = (const float*)d_in[2];
    const float* b1 = (const float*)d_in[3];
    const float* W2 = (const float*)d_in[4];
    const float* b2 = (const float*)d_in[5];
    float* out = (float*)d_out;

    const int n = N_NODES, E = NEDGES;
    const int* src = ei;
    const int* dst = ei + E;

    // Workspace layout (bytes), ~20.7 MB (byte-identical to verified r12):
    char* ws = (char*)d_ws;
    int*            deg  = (int*)(ws + 0);                 // 160000
    _Float16*       WT1  = (_Float16*)(ws + 163840);       // 32768  fp16 W1^T
    _Float16*       WT2  = (_Float16*)(ws + 196608);       // 16384  fp16 W2^T
    unsigned short* ssrc = (unsigned short*)(ws + 212992); // 5.12MB ushort bins
    _Float16*       xh   = (_Float16*)(ws + 5332992);      // 10.24MB fp16 x
    _Float16*       h2   = (_Float16*)(ws + 15572992);     // 5.12MB fp16 (scaled)

    hipMemsetAsync(deg, 0, N_NODES * sizeof(int), stream);
    k_bkt_cvt <<<NBUCKET + NCVT + NWT, 256, 0, stream>>>(x, xh, (const int4*)src,
                                                         (const int4*)dst, deg, ssrc,
                                                         W1, W2, WT1, WT2);
    k_agg_g12 <<<n / 16, 256, 0, stream>>>(deg, ssrc, xh, b1, WT1, WT2, h2);
    k_agg2    <<<n / 32, 256, 0, stream>>>(deg, ssrc, h2, b2, out);
}

// Round 9
// 158.833 us; speedup vs baseline: 1.1929x; 1.0494x over previous
//
#include <hip/hip_runtime.h>
#include <hip/hip_fp16.h>

// ClassicalGCN: 2-layer GCN, N=40000, E=640000, 128 -> 128(relu) -> 64, f32.
// Round 21: pure-sum gathers at 2x stream depth. Model (9 rounds stable):
// dur = ~45us harness poison fill (in-window, untouchable) + Sum(kernels).
// r20 Sum ~= 46(bkt_cvt) + 47.5(agg_g12) + 27(agg2).
//  - NEW k_scale: xh *= dinv[row] IN PLACE after bucket (deg final). Layer-1
//    gather becomes PURE SUM (r16-verified numerics): per-edge deg[s] load,
//    rsqrtf, weight FMAs all leave the inner loop.
//  - k_agg_g12 / k_agg2: 8-edge unroll (one group-uniform uint4 = 8 indices
//    per iter) -> 8 independent row-streams per group (32/wave L1, 64/wave
//    L2); pads select own row, 0/1 mask multiply.
//  - k_bkt_cvt unchanged (r19/r20 verified).
// 4 kernels + deg memset (launches ~2us each, r19-measured cheap).
// Workspace ~20.7MB, r12-verified offsets.

#define N_NODES 40000
#define DIN 128
#define DH 128
#define DOUT 64
#define NEDGES 640000
#define CAP 64             // bin capacity; realized max degree ~35
#define NBUCKET 2560       // 8 XCD groups x 320 chunks (r15/r19 verified)
#define I4_PER_CHUNK 500   // 160000 int4 / 320 chunks
#define NODES_PER_XCD 5000
#define NCVT 1250          // x->fp16 convert blocks
#define NWT 8              // WT1/WT2 transpose blocks

typedef _Float16 f16x8 __attribute__((ext_vector_type(8)));
typedef float f32x4 __attribute__((ext_vector_type(4)));

// ---- blocks [0,NBUCKET): bucket; [NBUCKET,+NCVT): x->fp16; last NWT: WT ----
__global__ __launch_bounds__(256) void k_bkt_cvt(
    const float* __restrict__ x, _Float16* __restrict__ xh,
    const int4* __restrict__ src4, const int4* __restrict__ dst4,
    int* __restrict__ deg, unsigned short* __restrict__ ssrc,
    const float* __restrict__ W1, const float* __restrict__ W2,
    _Float16* __restrict__ WT1, _Float16* __restrict__ WT2)
{
    if (blockIdx.x < NBUCKET) {
        // ---- bucket: this block only handles dst in its XCD's node range ----
        const int xg = blockIdx.x & 7;            // presumed XCD id (heuristic)
        const int c  = blockIdx.x >> 3;           // edge chunk 0..319
        const int lo = xg * NODES_PER_XCD, hi = lo + NODES_PER_XCD;
        const int e0 = c * I4_PER_CHUNK, e1 = e0 + I4_PER_CHUNK;
        for (int e = e0 + threadIdx.x; e < e1; e += 256) {
            int4 d = dst4[e];
            int4 s = src4[e];
            if (d.x >= lo && d.x < hi) {
                int p = atomicAdd(&deg[d.x], 1);
                if (p < CAP) ssrc[d.x * CAP + p] = (unsigned short)s.x;
            }
            if (d.y >= lo && d.y < hi) {
                int p = atomicAdd(&deg[d.y], 1);
                if (p < CAP) ssrc[d.y * CAP + p] = (unsigned short)s.y;
            }
            if (d.z >= lo && d.z < hi) {
                int p = atomicAdd(&deg[d.z], 1);
                if (p < CAP) ssrc[d.z * CAP + p] = (unsigned short)s.z;
            }
            if (d.w >= lo && d.w < hi) {
                int p = atomicAdd(&deg[d.w], 1);
                if (p < CAP) ssrc[d.w * CAP + p] = (unsigned short)s.w;
            }
        }
    } else if (blockIdx.x < NBUCKET + NCVT) {
        // ---- convert: 16 f32 per thread, coalesced float4 -> f16x8 ----
        const size_t base = ((size_t)(blockIdx.x - NBUCKET) * 256 + threadIdx.x) * 16;
        float4 a0 = *(const float4*)(x + base);
        float4 a1 = *(const float4*)(x + base + 4);
        float4 a2 = *(const float4*)(x + base + 8);
        float4 a3 = *(const float4*)(x + base + 12);
        f16x8 o0 = { (_Float16)a0.x, (_Float16)a0.y, (_Float16)a0.z, (_Float16)a0.w,
                     (_Float16)a1.x, (_Float16)a1.y, (_Float16)a1.z, (_Float16)a1.w };
        f16x8 o1 = { (_Float16)a2.x, (_Float16)a2.y, (_Float16)a2.z, (_Float16)a2.w,
                     (_Float16)a3.x, (_Float16)a3.y, (_Float16)a3.z, (_Float16)a3.w };
        *(f16x8*)(xh + base)     = o0;
        *(f16x8*)(xh + base + 8) = o1;
    } else {
        // ---- WT transposes: WT1[n][k]=fp16(W1[k][n]), WT2[n][k]=fp16(W2[k][n])
        const int b = blockIdx.x - NBUCKET - NCVT;   // 0..7
        for (int i = b * 256 + threadIdx.x; i < DIN * DH; i += NWT * 256) {
            int k = i >> 7, nn = i & 127;
            WT1[nn * DIN + k] = (_Float16)W1[i];
        }
        for (int i = b * 256 + threadIdx.x; i < DH * DOUT; i += NWT * 256) {
            int k = i >> 6, nn = i & 63;
            WT2[nn * DH + k] = (_Float16)W2[i];
        }
    }
}

// ---- scale: xh[row][:] *= rsqrt(deg[row]+1), in place (8 halfs/thread) ----
__global__ __launch_bounds__(256) void k_scale(
    _Float16* __restrict__ xh, const int* __restrict__ deg)
{
    int idx = blockIdx.x * 256 + threadIdx.x;     // one per 8 halfs
    int row = idx >> 4;                           // 16 threads per 128-col row
    float dn = rsqrtf((float)(deg[row] + 1));
    f16x8 v = *(f16x8*)(xh + (size_t)idx * 8);
    f16x8 o;
#pragma unroll
    for (int j = 0; j < 8; ++j) o[j] = (_Float16)((float)v[j] * dn);
    *(f16x8*)(xh + (size_t)idx * 8) = o;
}

// ---- agg1 (8 streams/group, pure sum) + gemm1(+b1,relu) + gemm2(*dinv).
// Block = 16 nodes = 4 waves x 4 groups(16 lanes); group owns one node;
// lane gl covers halfs [gl*8, gl*8+8) of the 128-col row.
__global__ __launch_bounds__(256) void k_agg_g12(
    const int* __restrict__ deg, const unsigned short* __restrict__ ssrc,
    const _Float16* __restrict__ xh, const float* __restrict__ b1,
    const _Float16* __restrict__ WT1, const _Float16* __restrict__ WT2,
    _Float16* __restrict__ h2)
{
    __shared__ _Float16 ys[16][136];   // aggregated input tile (+8 pad)
    __shared__ _Float16 zs[16][136];   // post-relu hidden tile (+8 pad)
    const int w = threadIdx.x >> 6;    // wave 0..3
    const int lane = threadIdx.x & 63;
    const int g  = lane >> 4;          // group 0..3 -> node
    const int gl = lane & 15;          // lane in group -> col chunk
    const int node0 = blockIdx.x * 16;
    const int node = node0 + w * 4 + g;

    const int dg = deg[node];
    const int cnt = min(dg, CAP);
    const float dn = rsqrtf((float)(dg + 1));

    float ac[8];
    {
        f16x8 self = *(const f16x8*)(xh + (size_t)node * DIN + gl * 8);
#pragma unroll
        for (int j = 0; j < 8; ++j) ac[j] = (float)self[j];  // xsc[d] (pre-scaled)
    }
    // wave-max cnt so all lanes loop together; pads masked to 0
    int mc = cnt;
    mc = max(mc, __shfl_xor(mc, 16));
    mc = max(mc, __shfl_xor(mc, 32));

    const unsigned short* bin = ssrc + (size_t)node * CAP;
    for (int e = 0; e < mc; e += 8) {
        uint4 pk = *(const uint4*)(bin + e);      // group-uniform, 8 indices
        int s0 = (int)(pk.x & 0xFFFF), s1 = (int)(pk.x >> 16);
        int s2 = (int)(pk.y & 0xFFFF), s3 = (int)(pk.y >> 16);
        int s4 = (int)(pk.z & 0xFFFF), s5 = (int)(pk.z >> 16);
        int s6 = (int)(pk.w & 0xFFFF), s7 = (int)(pk.w >> 16);
        float m0 = (e + 0 < cnt) ? 1.f : 0.f;  s0 = (e + 0 < cnt) ? s0 : node;
        float m1 = (e + 1 < cnt) ? 1.f : 0.f;  s1 = (e + 1 < cnt) ? s1 : node;
        float m2 = (e + 2 < cnt) ? 1.f : 0.f;  s2 = (e + 2 < cnt) ? s2 : node;
        float m3 = (e + 3 < cnt) ? 1.f : 0.f;  s3 = (e + 3 < cnt) ? s3 : node;
        float m4 = (e + 4 < cnt) ? 1.f : 0.f;  s4 = (e + 4 < cnt) ? s4 : node;
        float m5 = (e + 5 < cnt) ? 1.f : 0.f;  s5 = (e + 5 < cnt) ? s5 : node;
        float m6 = (e + 6 < cnt) ? 1.f : 0.f;  s6 = (e + 6 < cnt) ? s6 : node;
        float m7 = (e + 7 < cnt) ? 1.f : 0.f;  s7 = (e + 7 < cnt) ? s7 : node;
        f16x8 r0 = *(const f16x8*)(xh + (size_t)s0 * DIN + gl * 8);
        f16x8 r1 = *(const f16x8*)(xh + (size_t)s1 * DIN + gl * 8);
        f16x8 r2 = *(const f16x8*)(xh + (size_t)s2 * DIN + gl * 8);
        f16x8 r3 = *(const f16x8*)(xh + (size_t)s3 * DIN + gl * 8);
        f16x8 r4 = *(const f16x8*)(xh + (size_t)s4 * DIN + gl * 8);
        f16x8 r5 = *(const f16x8*)(xh + (size_t)s5 * DIN + gl * 8);
        f16x8 r6 = *(const f16x8*)(xh + (size_t)s6 * DIN + gl * 8);
        f16x8 r7 = *(const f16x8*)(xh + (size_t)s7 * DIN + gl * 8);
#pragma unroll
        for (int j = 0; j < 8; ++j) {
            ac[j] += (m0 * (float)r0[j] + m1 * (float)r1[j])
                   + (m2 * (float)r2[j] + m3 * (float)r3[j]);
            ac[j] += (m4 * (float)r4[j] + m5 * (float)r5[j])
                   + (m6 * (float)r6[j] + m7 * (float)r7[j]);
        }
    }
    // ys row = dn * ac  (bias after gemm1)
    {
        f16x8 o;
#pragma unroll
        for (int j = 0; j < 8; ++j) o[j] = (_Float16)(dn * ac[j]);
        *(f16x8*)&ys[w * 4 + g][gl * 8] = o;
    }
    __syncthreads();

    const int m = lane & 15, quad = lane >> 4;
#pragma unroll
    for (int t = 0; t < 2; ++t) {
        // ---- gemm1: wave w covers hidden cols (2w+t)*16 .. +15 ----
        const int nt = w * 2 + t;
        f32x4 acc1 = (f32x4){0.f, 0.f, 0.f, 0.f};
#pragma unroll
        for (int ks = 0; ks < 4; ++ks) {
            f16x8 a = *(const f16x8*)&ys[m][ks * 32 + quad * 8];
            f16x8 b = *(const f16x8*)(WT1 + (size_t)(nt * 16 + m) * DIN + ks * 32 + quad * 8);
            acc1 = __builtin_amdgcn_mfma_f32_16x16x32_f16(a, b, acc1, 0, 0, 0);
        }
        float bias = b1[nt * 16 + m];
#pragma unroll
        for (int r = 0; r < 4; ++r) {
            float v = acc1[r] + bias;
            zs[quad * 4 + r][nt * 16 + m] = (_Float16)(v > 0.f ? v : 0.f);
        }
    }
    __syncthreads();

    {
        // ---- gemm2: wave w covers out cols w*16 .. +15; h2 pre-scaled ----
        f32x4 acc2 = (f32x4){0.f, 0.f, 0.f, 0.f};
#pragma unroll
        for (int ks = 0; ks < 4; ++ks) {
            f16x8 a = *(const f16x8*)&zs[m][ks * 32 + quad * 8];
            f16x8 b = *(const f16x8*)(WT2 + (size_t)(w * 16 + m) * DH + ks * 32 + quad * 8);
            acc2 = __builtin_amdgcn_mfma_f32_16x16x32_f16(a, b, acc2, 0, 0, 0);
        }
#pragma unroll
        for (int r = 0; r < 4; ++r) {
            int nrow = node0 + quad * 4 + r;
            float dnr = rsqrtf((float)(deg[nrow] + 1));
            h2[(size_t)nrow * DOUT + w * 16 + m] = (_Float16)(acc2[r] * dnr);
        }
    }
}

// ---- agg2: 8 groups/wave x 8 streams over pre-scaled h2 (64 cols/row).
// Block = 32 nodes = 4 waves x 8 groups(8 lanes).
__global__ __launch_bounds__(256) void k_agg2(
    const int* __restrict__ deg, const unsigned short* __restrict__ ssrc,
    const _Float16* __restrict__ h2, const float* __restrict__ b2,
    float* __restrict__ out)
{
    const int w = threadIdx.x >> 6;
    const int lane = threadIdx.x & 63;
    const int g  = lane >> 3;          // group 0..7 -> node
    const int gl = lane & 7;           // col chunk (8 halfs)
    const int node = blockIdx.x * 32 + w * 8 + g;

    const int dg = deg[node];
    const int cnt = min(dg, CAP);
    const float dn = rsqrtf((float)(dg + 1));

    float ac[8];
    {
        f16x8 self = *(const f16x8*)(h2 + (size_t)node * DOUT + gl * 8);
#pragma unroll
        for (int j = 0; j < 8; ++j) ac[j] = (float)self[j];   // self (pre-scaled)
    }
    int mc = cnt;
    mc = max(mc, __shfl_xor(mc, 8));
    mc = max(mc, __shfl_xor(mc, 16));
    mc = max(mc, __shfl_xor(mc, 32));

    const unsigned short* bin = ssrc + (size_t)node * CAP;
    for (int e = 0; e < mc; e += 8) {
        uint4 pk = *(const uint4*)(bin + e);      // group-uniform, 8 indices
        int s0 = (int)(pk.x & 0xFFFF), s1 = (int)(pk.x >> 16);
        int s2 = (int)(pk.y & 0xFFFF), s3 = (int)(pk.y >> 16);
        int s4 = (int)(pk.z & 0xFFFF), s5 = (int)(pk.z >> 16);
        int s6 = (int)(pk.w & 0xFFFF), s7 = (int)(pk.w >> 16);
        float m0 = (e + 0 < cnt) ? 1.f : 0.f;  s0 = (e + 0 < cnt) ? s0 : node;
        float m1 = (e + 1 < cnt) ? 1.f : 0.f;  s1 = (e + 1 < cnt) ? s1 : node;
        float m2 = (e + 2 < cnt) ? 1.f : 0.f;  s2 = (e + 2 < cnt) ? s2 : node;
        float m3 = (e + 3 < cnt) ? 1.f : 0.f;  s3 = (e + 3 < cnt) ? s3 : node;
        float m4 = (e + 4 < cnt) ? 1.f : 0.f;  s4 = (e + 4 < cnt) ? s4 : node;
        float m5 = (e + 5 < cnt) ? 1.f : 0.f;  s5 = (e + 5 < cnt) ? s5 : node;
        float m6 = (e + 6 < cnt) ? 1.f : 0.f;  s6 = (e + 6 < cnt) ? s6 : node;
        float m7 = (e + 7 < cnt) ? 1.f : 0.f;  s7 = (e + 7 < cnt) ? s7 : node;
        f16x8 r0 = *(const f16x8*)(h2 + (size_t)s0 * DOUT + gl * 8);
        f16x8 r1 = *(const f16x8*)(h2 + (size_t)s1 * DOUT + gl * 8);
        f16x8 r2 = *(const f16x8*)(h2 + (size_t)s2 * DOUT + gl * 8);
        f16x8 r3 = *(const f16x8*)(h2 + (size_t)s3 * DOUT + gl * 8);
        f16x8 r4 = *(const f16x8*)(h2 + (size_t)s4 * DOUT + gl * 8);
        f16x8 r5 = *(const f16x8*)(h2 + (size_t)s5 * DOUT + gl * 8);
        f16x8 r6 = *(const f16x8*)(h2 + (size_t)s6 * DOUT + gl * 8);
        f16x8 r7 = *(const f16x8*)(h2 + (size_t)s7 * DOUT + gl * 8);
#pragma unroll
        for (int j = 0; j < 8; ++j) {
            ac[j] += (m0 * (float)r0[j] + m1 * (float)r1[j])
                   + (m2 * (float)r2[j] + m3 * (float)r3[j]);
            ac[j] += (m4 * (float)r4[j] + m5 * (float)r5[j])
                   + (m6 * (float)r6[j] + m7 * (float)r7[j]);
        }
    }
    // out = dn*ac + b2
    float4 ba = *(const float4*)(b2 + gl * 8);
    float4 bb = *(const float4*)(b2 + gl * 8 + 4);
    float4 o0 = { dn * ac[0] + ba.x, dn * ac[1] + ba.y,
                  dn * ac[2] + ba.z, dn * ac[3] + ba.w };
    float4 o1 = { dn * ac[4] + bb.x, dn * ac[5] + bb.y,
                  dn * ac[6] + bb.z, dn * ac[7] + bb.w };
    float* orow = out + (size_t)node * DOUT + gl * 8;
    *(float4*)orow = o0;
    *(float4*)(orow + 4) = o1;
}

extern "C" void kernel_launch(void* const* d_in, const int* in_sizes, int n_in,
                              void* d_out, int out_size, void* d_ws, size_t ws_size,
                              hipStream_t stream) {
    const float* x  = (const float*)d_in[0];
    const int*   ei = (const int*)d_in[1];   // [2, E] int32
    const float* W1 = (const float*)d_in[2];
    const float* b1 = (const float*)d_in[3];
    const float* W2 = (const float*)d_in[4];
    const float* b2 = (const float*)d_in[5];
    float* out = (float*)d_out;

    const int n = N_NODES, E = NEDGES;
    const int* src = ei;
    const int* dst = ei + E;

    // Workspace layout (bytes), ~20.7 MB (byte-identical to verified r12):
    char* ws = (char*)d_ws;
    int*            deg  = (int*)(ws + 0);                 // 160000
    _Float16*       WT1  = (_Float16*)(ws + 163840);       // 32768  fp16 W1^T
    _Float16*       WT2  = (_Float16*)(ws + 196608);       // 16384  fp16 W2^T
    unsigned short* ssrc = (unsigned short*)(ws + 212992); // 5.12MB ushort bins
    _Float16*       xh   = (_Float16*)(ws + 5332992);      // 10.24MB fp16 x
    _Float16*       h2   = (_Float16*)(ws + 15572992);     // 5.12MB fp16 (scaled)

    hipMemsetAsync(deg, 0, N_NODES * sizeof(int), stream);
    k_bkt_cvt <<<NBUCKET + NCVT + NWT, 256, 0, stream>>>(x, xh, (const int4*)src,
                                                         (const int4*)dst, deg, ssrc,
                                                         W1, W2, WT1, WT2);
    k_scale   <<<(N_NODES * DIN / 8) / 256, 256, 0, stream>>>(xh, deg);
    k_agg_g12 <<<n / 16, 256, 0, stream>>>(deg, ssrc, xh, b1, WT1, WT2, h2);
    k_agg2    <<<n / 32, 256, 0, stream>>>(deg, ssrc, h2, b2, out);
}